// Round 6
// baseline (183.986 us; speedup 1.0000x reference)
//
#include <hip/hip_runtime.h>
#include <hip/hip_bf16.h>
#include <math.h>

// Problem constants (from reference): B=4, T=8192, D=512, S=16
#define B_ 4
#define T_ 8192
#define D_ 512
#define S_ 16

// tokens per block for attn_ts_k (32 -> 1024 blocks = 4 blocks/CU at <=64 regs)
#define CHUNK 32

// ---------------------------------------------------------------------------
// JOURNAL (measured, gfx950):
// R0: attn(VALU,124regs)=57.7us, total 177.5.
// R1: launch_bounds cap below true need SPILLS (hbm 82->470MB). Never.
// R2: attn CHUNK=32 VALU = 50.4us. out float4 ssf crossed 64-reg step: 195.
// R3: lane-per-(token,splat): 16 lanes share x addr -> VMEM-issue-bound, 80us.
// R4: out_k LDS-staged+(256,4): rest ~12us worse than R0. attn 52. total 183.
// R5: phase A -> MFMA: attn ~45us, VGPR 68 (4 over the step! cf[16] held
//     pointlessly across K-loop), occupancy still 17% (512 blocks = 2/CU
//     grid cap). total 179.5. MFMA port CORRECT (absmax 0.125 pass).
// OCCUPANCY LAW: VGPR<=64 -> 4 w/SIMD; 65..128 -> 2 w/SIMD. Grid must also
// supply >=4 blocks/CU (1024 blocks at 256 thr).
// R6: CHUNK=32 + K-split: wave pair (w,w+2) = same 16 tokens, disjoint
//     K-halves; combine acc4+x2+c2 via 6KB LDS + 1 barrier. c-fragments
//     loaded inside K-loop (each used once -> no reason to hold 64 regs).
//     (256,4) cap, true need ~55. out_k: K4_TOK 64->32 (1024 blocks),
//     body untouched.
// ---------------------------------------------------------------------------

typedef __attribute__((ext_vector_type(8))) short bf16x8;   // 8 bf16 (4 VGPRs)
typedef __attribute__((ext_vector_type(4))) float f32x4;    // mfma C/D

__device__ __forceinline__ float dot4(float4 a, float4 b) {
  return a.x * b.x + a.y * b.y + a.z * b.z + a.w * b.w;
}

// pack 8 fp32 -> 8 bf16 (RNE), as the short8 the mfma builtin takes
__device__ __forceinline__ bf16x8 pack8(float4 a, float4 b) {
  union { __hip_bfloat162 h[4]; bf16x8 v; } u;
  u.h[0] = __float22bfloat162_rn(make_float2(a.x, a.y));
  u.h[1] = __float22bfloat162_rn(make_float2(a.z, a.w));
  u.h[2] = __float22bfloat162_rn(make_float2(b.x, b.y));
  u.h[3] = __float22bfloat162_rn(make_float2(b.z, b.w));
  return u.v;
}

// ---------------------------------------------------------------------------
// Fused attn + token->splat aggregation. 1024 blocks x 256 threads (4 waves).
//
// Phase A (MFMA, K-split): waves {w, w+2} both own tokens t0+16*(w&1)..+15;
// wave w covers K subtiles (w>>1)*8..+7. Per wave: 8 x mfma_f32_16x16x32_bf16
// with A=x rows, B=centers^T cols; x2/c2 fp32 side-sums from the same loads
// (verified R5). Partials {acc[4], x2, c2} -> LDS; barrier; waves 0,1 combine
// their pair, do softmax (verified xor-1/2/4/8 form), store attn + a_s.
// D-layout: lane holds splat n=lane&15, token rows (lane>>4)*4+r [m89].
//
// Phase B: EXACT R2 phase B (proven): thread owns cols d,d+256; streams
// chunk's x rows (L2-hot) against LDS-broadcast attn; atomicAdds into ts.
// ---------------------------------------------------------------------------
__global__ __launch_bounds__(256, 4) void attn_ts_k(const float* __restrict__ x,
                                                    const float* __restrict__ centers,
                                                    const float* __restrict__ log_scales,
                                                    float* __restrict__ attn,
                                                    float* __restrict__ ts) {
  __shared__ __align__(16) float a_s[CHUNK][S_];  // 2 KB
  __shared__ float red[6][4][64];                 // 6 KB: acc0..3, x2, c2
  const int tid = threadIdx.x;
  const int lane = tid & 63;
  const int w = tid >> 6;        // wave 0..3
  const int g = lane >> 4;       // k-group 0..3
  const int n = lane & 15;       // A-row token idx == B-col splat idx
  const int b = blockIdx.x >> 8;              // 256 chunks per batch
  const int t0 = (blockIdx.x & 255) * CHUNK;  // 32 tokens per block
  const int pair = w & 1;                     // which 16-token group
  const int half = w >> 1;                    // which K-half (256 floats)
  const int tw = t0 + (pair << 4);

  // ---- Phase A: per-wave partial over its K-half ----
  {
    const float* crow = centers + n * D_ + (half << 8) + (g << 3);
    const float* xrow = x + ((size_t)b * T_ + tw + n) * D_ + (half << 8) + (g << 3);
    f32x4 acc = {0.f, 0.f, 0.f, 0.f};
    float x2p = 0.f, c2p = 0.f;
#pragma unroll
    for (int st = 0; st < 8; ++st) {
      float4 x0 = *(const float4*)(xrow + st * 32);
      float4 x1 = *(const float4*)(xrow + st * 32 + 4);
      float4 c0 = *(const float4*)(crow + st * 32);
      float4 c1 = *(const float4*)(crow + st * 32 + 4);
      x2p += dot4(x0, x0) + dot4(x1, x1);
      c2p += dot4(c0, c0) + dot4(c1, c1);
      acc = __builtin_amdgcn_mfma_f32_16x16x32_bf16(pack8(x0, x1), pack8(c0, c1),
                                                    acc, 0, 0, 0);
    }
    // complete x2/c2 partials across k-groups within this wave's K-half
    x2p += __shfl_xor(x2p, 16, 64);
    x2p += __shfl_xor(x2p, 32, 64);  // x2 half-sum for token tw+n (all lanes)
    c2p += __shfl_xor(c2p, 16, 64);
    c2p += __shfl_xor(c2p, 32, 64);  // c2 half-sum for splat n

    red[0][w][lane] = acc[0];
    red[1][w][lane] = acc[1];
    red[2][w][lane] = acc[2];
    red[3][w][lane] = acc[3];
    red[4][w][lane] = x2p;
    red[5][w][lane] = c2p;
  }
  __syncthreads();

  // ---- combine + softmax on waves 0,1 (waves 2,3 wait at next barrier) ----
  if (w < 2) {
    float accr[4];
#pragma unroll
    for (int r = 0; r < 4; ++r) accr[r] = red[r][w][lane] + red[r][w + 2][lane];
    float x2 = red[4][w][lane] + red[4][w + 2][lane];
    float c2 = red[5][w][lane] + red[5][w + 2][lane];

    const float sc = fminf(fmaxf(__expf(log_scales[n]), 0.1f), 2.0f);
    const float inv2 = 0.5f / (sc * sc);

    // logits: lane holds splat n, token rows (g*4+r)
    float lg[4];
#pragma unroll
    for (int r = 0; r < 4; ++r) {
      float x2r = __shfl(x2, (lane & 48) | ((g << 2) + r), 64);
      lg[r] = (2.f * accr[r] - x2r - c2) * inv2;
    }

    // softmax across splats (16-lane groups), 4 tokens per lane (verified R5)
    float mx[4] = {lg[0], lg[1], lg[2], lg[3]};
#pragma unroll
    for (int dlt = 1; dlt < 16; dlt <<= 1)
#pragma unroll
      for (int r = 0; r < 4; ++r) mx[r] = fmaxf(mx[r], __shfl_xor(mx[r], dlt, 64));
    float ev[4], sm[4];
#pragma unroll
    for (int r = 0; r < 4; ++r) { ev[r] = __expf(lg[r] - mx[r]); sm[r] = ev[r]; }
#pragma unroll
    for (int dlt = 1; dlt < 16; dlt <<= 1)
#pragma unroll
      for (int r = 0; r < 4; ++r) sm[r] += __shfl_xor(sm[r], dlt, 64);

    float* ar = attn + ((size_t)b * T_ + tw) * S_;
#pragma unroll
    for (int r = 0; r < 4; ++r) {
      float av = ev[r] / sm[r];
      int trow = (g << 2) + r;
      ar[trow * S_ + n] = av;
      a_s[(pair << 4) + trow][n] = av;
    }
  }

  __syncthreads();

  // ---- Phase B (exact R2, proven) ----
  {
    const int d = tid;  // owns cols d and d+256
    float2 acc[S_];
#pragma unroll
    for (int si = 0; si < S_; ++si) acc[si] = make_float2(0.f, 0.f);

    const float* xb = x + ((size_t)b * T_ + t0) * D_;

#pragma unroll 8
    for (int t = 0; t < CHUNK; ++t) {
      float xv0 = xb[(size_t)t * D_ + d];
      float xv1 = xb[(size_t)t * D_ + d + 256];
      const float4* ap = (const float4*)a_s[t];  // LDS broadcast
      float4 q0 = ap[0], q1 = ap[1], q2 = ap[2], q3 = ap[3];
      float av[S_] = {q0.x, q0.y, q0.z, q0.w, q1.x, q1.y, q1.z, q1.w,
                      q2.x, q2.y, q2.z, q2.w, q3.x, q3.y, q3.z, q3.w};
#pragma unroll
      for (int si = 0; si < S_; ++si) {
        acc[si].x += av[si] * xv0;
        acc[si].y += av[si] * xv1;
      }
    }

    float* tb = ts + (size_t)b * S_ * D_;
#pragma unroll
    for (int si = 0; si < S_; ++si) {
      atomicAdd(tb + si * D_ + d, acc[si].x);
      atomicAdd(tb + si * D_ + d + 256, acc[si].y);
    }
  }
}

// ---------------------------------------------------------------------------
// Kernel 2 (x2): out[r,e] = sum_k in[r,k] * W[e,k]   (r = 0..63 = b*S+s)
// Split-K=4 reduced in LDS (deterministic). 512 blocks x 256 threads.
// ---------------------------------------------------------------------------
__global__ __launch_bounds__(256) void proj_k(const float* __restrict__ in,
                                              const float* __restrict__ W,
                                              float* __restrict__ out) {
  __shared__ float red[4][64];
  const int r = blockIdx.x >> 3;
  const int eb = blockIdx.x & 7;
  const int el = threadIdx.x & 63;
  const int kc = threadIdx.x >> 6;
  const int e = (eb << 6) + el;

  const float4* w4 = (const float4*)(W + (size_t)e * D_ + kc * 128);
  const float4* i4 = (const float4*)(in + (size_t)r * D_ + kc * 128);
  float acc = 0.f;
#pragma unroll
  for (int k = 0; k < 32; ++k) acc += dot4(w4[k], i4[k]);

  red[kc][el] = acc;
  __syncthreads();
  if (kc == 0)
    out[(size_t)r * D_ + e] = red[0][el] + red[1][el] + red[2][el] + red[3][el];
}

// ---------------------------------------------------------------------------
// Kernel 3: out[b,t,e] = sum_s attn[b,t,s] * ss_o[b,s,e]
// R0 body EXACTLY; only K4_TOK 64->32 (1024 blocks) so the grid supplies
// 4 blocks/CU if natural VGPR <= 64 (the R0 grid of 512 hard-capped
// residency at 2 blocks/CU regardless of registers). No min-waves hint.
// ---------------------------------------------------------------------------
#define K4_TOK 32
__global__ __launch_bounds__(256) void out_k(const float* __restrict__ attn,
                                             const float* __restrict__ ss_o,
                                             float* __restrict__ out) {
  const int chunks = T_ / K4_TOK;  // 256
  const int b = blockIdx.x / chunks;
  const int t0 = (blockIdx.x % chunks) * K4_TOK;
  const int w = threadIdx.x >> 6;
  const int lane = threadIdx.x & 63;
  const int e0 = (w << 7) + (lane << 1);

  float2 ssf[S_];
  const float* sb = ss_o + (size_t)b * S_ * D_;
#pragma unroll
  for (int s = 0; s < S_; ++s) ssf[s] = *(const float2*)(sb + s * D_ + e0);

  const float4* ab = (const float4*)(attn + ((size_t)b * T_ + t0) * S_);
  float* ob = out + ((size_t)b * T_ + t0) * D_ + e0;

#pragma unroll 4
  for (int t = 0; t < K4_TOK; ++t) {
    float4 a0 = ab[t * 4 + 0], a1 = ab[t * 4 + 1];
    float4 a2 = ab[t * 4 + 2], a3 = ab[t * 4 + 3];
    float av[S_] = {a0.x, a0.y, a0.z, a0.w, a1.x, a1.y, a1.z, a1.w,
                    a2.x, a2.y, a2.z, a2.w, a3.x, a3.y, a3.z, a3.w};
    float2 acc = make_float2(0.f, 0.f);
#pragma unroll
    for (int s = 0; s < S_; ++s) {
      acc.x += av[s] * ssf[s].x;
      acc.y += av[s] * ssf[s].y;
    }
    *(float2*)(ob + (size_t)t * D_) = acc;
  }
}

// ---------------------------------------------------------------------------
extern "C" void kernel_launch(void* const* d_in, const int* in_sizes, int n_in,
                              void* d_out, int out_size, void* d_ws, size_t ws_size,
                              hipStream_t stream) {
  const float* x          = (const float*)d_in[0];  // [B,T,D]
  const float* centers    = (const float*)d_in[1];  // [S,D]
  const float* log_scales = (const float*)d_in[2];  // [S]
  const float* Wv         = (const float*)d_in[3];  // [D,D]
  const float* Wo         = (const float*)d_in[4];  // [D,D]
  float* out = (float*)d_out;                       // [B,T,D]

  // workspace layout (floats): attn | ts | tmp | ss_o
  float* attn = (float*)d_ws;                        // B*T*S   = 2 MB
  float* ts   = attn + (size_t)B_ * T_ * S_;         // B*S*D   = 128 KB
  float* tmp  = ts + (size_t)B_ * S_ * D_;           // B*S*D   = 128 KB
  float* ss_o = tmp + (size_t)B_ * S_ * D_;          // B*S*D   = 128 KB

  // zero only the atomic target (tiny, L2-resident fill)
  hipMemsetAsync(ts, 0, (size_t)B_ * S_ * D_ * sizeof(float), stream);

  attn_ts_k<<<B_ * (T_ / CHUNK), 256, 0, stream>>>(x, centers, log_scales, attn, ts);
  proj_k<<<512, 256, 0, stream>>>(ts, Wv, tmp);    // tmp = ts @ Wv^T
  proj_k<<<512, 256, 0, stream>>>(tmp, Wo, ss_o);  // ss_o = tmp @ Wo^T
  out_k<<<B_ * (T_ / K4_TOK), 256, 0, stream>>>(attn, ss_o, out);
}

// Round 8
// 176.405 us; speedup vs baseline: 1.0430x; 1.0430x over previous
//
#include <hip/hip_runtime.h>
#include <hip/hip_bf16.h>
#include <math.h>

// Problem constants (from reference): B=4, T=8192, D=512, S=16
#define B_ 4
#define T_ 8192
#define D_ 512
#define S_ 16

// tokens per block for attn_ts_k (64 -> 512 blocks, 4 waves x 16 tokens)
#define CHUNK 64

// ---------------------------------------------------------------------------
// JOURNAL (measured, gfx950):
// R0: attn(VALU,124regs)=57.7us, total 177.5.
// R1: launch_bounds cap below true need SPILLS (hbm 82->470MB). Never.
// R2: attn CHUNK=32 VALU = 50.4us. out float4 ssf crossed 64-reg step: 195.
// R3: lane-per-(token,splat): 16 lanes share x addr -> VMEM-issue-bound, 80us.
// R4: out_k LDS-staged+(256,4): rest ~12us worse than R0. attn 52. total 183.
// R5: phase A -> MFMA (verified): attn ~45us, VGPR 68, occ 17%. total 179.5.
// R6: K-split occupancy fix: VGPR 36, occ 30% -- attn 50us, WORSE. Occupancy
//     is NOT the binding constraint. R5 structure is the better host.
//     Phase A is issue-throttled: ~28 VALU/K-step (4x redundant c-side work).
// R7: container infra failure (no kernel signal). Resubmitted with LDS
//     atomicAdd c2 replaced by deterministic wave-0 shuffle-reduce.
//     Design: (a) center-fragments packed ONCE per block into LDS (16KB),
//     K-step = 2 x-loads + ds_read + pack + mfma; (b) x2 dropped when scales
//     uniform (softmax-invariant shift; log_scales==0 here; ballot check,
//     R5-verified full path as fallback). Shape: R5 (CHUNK=64, 512 blk,
//     (256,2)). out_k = exact R0. OCCUPANCY LAW: VGPR<=64 -> 4 w/SIMD;
//     65..128 -> 2 w/SIMD; grid must supply the blocks.
// ---------------------------------------------------------------------------

typedef __attribute__((ext_vector_type(8))) short bf16x8;   // 8 bf16 (4 VGPRs)
typedef __attribute__((ext_vector_type(4))) float f32x4;    // mfma C/D

__device__ __forceinline__ float dot4(float4 a, float4 b) {
  return a.x * b.x + a.y * b.y + a.z * b.z + a.w * b.w;
}

// pack 8 fp32 -> 8 bf16 (RNE), as the short8 the mfma builtin takes
__device__ __forceinline__ bf16x8 pack8(float4 a, float4 b) {
  union { __hip_bfloat162 h[4]; bf16x8 v; } u;
  u.h[0] = __float22bfloat162_rn(make_float2(a.x, a.y));
  u.h[1] = __float22bfloat162_rn(make_float2(a.z, a.w));
  u.h[2] = __float22bfloat162_rn(make_float2(b.x, b.y));
  u.h[3] = __float22bfloat162_rn(make_float2(b.z, b.w));
  return u.v;
}

// ---------------------------------------------------------------------------
// Fused attn + token->splat aggregation. 512 blocks x 256 threads (4 waves).
//
// Setup: block cooperatively packs centers into LDS B-fragments
//   cf_s[st][lane]: lane=(g,n) holds centers[n][st*32+g*8 .. +7] as bf16x8.
//   c2[n] computed deterministically by wave 0 (R5-verified shuffle form).
//
// Phase A (MFMA): wave w owns tokens tw..tw+15. K-loop (16 steps):
//   load 32B of x row (token tw+n), pack, ds_read cf, one
//   mfma_f32_16x16x32_bf16. D-layout: lane holds splat n=lane&15, token
//   rows (lane>>4)*4+r [m89-verified, R5-proven]. If scales are uniform
//   (ballot check; true here: log_scales==0) the x2 term is a per-token
//   constant in the softmax and is skipped entirely; otherwise the
//   R5-verified x2 side-sum path runs.
//
// Phase B: EXACT R0/R5 (proven): thread owns cols d,d+256; streams chunk's
// x rows (L2-hot) against LDS-broadcast attn; atomicAdds into ts.
// ---------------------------------------------------------------------------
__global__ __launch_bounds__(256, 2) void attn_ts_k(const float* __restrict__ x,
                                                    const float* __restrict__ centers,
                                                    const float* __restrict__ log_scales,
                                                    float* __restrict__ attn,
                                                    float* __restrict__ ts) {
  __shared__ __align__(16) float a_s[CHUNK][S_];   // 4 KB
  __shared__ __align__(16) bf16x8 cf_s[16][64];    // 16 KB packed B-fragments
  __shared__ float c2_s[S_];
  const int tid = threadIdx.x;
  const int lane = tid & 63;
  const int w = tid >> 6;   // wave 0..3
  const int g = lane >> 4;  // k-group 0..3
  const int n = lane & 15;  // A-row token idx == B-col splat idx
  const int b = blockIdx.x >> 7;              // 128 chunks per batch
  const int t0 = (blockIdx.x & 127) * CHUNK;  // 64 tokens per block
  const int tw = t0 + (w << 4);               // this wave's 16 tokens

  // ---- cooperative center staging (once per block) ----
  // 1024 fragment slots = 4 per thread; thread handles (st, ln) entries.
#pragma unroll
  for (int i = 0; i < 4; ++i) {
    int e = i * 256 + tid;         // (st, lane-slot) entry 0..1023
    int st = e >> 6;
    int ln = e & 63;
    int nn = ln & 15, gg = ln >> 4;
    const float* src = centers + nn * D_ + st * 32 + (gg << 3);
    float4 c0 = *(const float4*)(src);
    float4 c1 = *(const float4*)(src + 4);
    cf_s[st][ln] = pack8(c0, c1);
  }
  // deterministic c2 on wave 0: lane (g,n) sums quarter g of centers row n,
  // xor-16/32 completes (exact R5-verified pattern), lane<16 writes.
  if (w == 0) {
    const float* crow = centers + n * D_ + (g << 7);
    float c2p = 0.f;
#pragma unroll
    for (int k = 0; k < 32; ++k) {
      float4 cv = *(const float4*)(crow + (k << 2));
      c2p += dot4(cv, cv);
    }
    c2p += __shfl_xor(c2p, 16, 64);
    c2p += __shfl_xor(c2p, 32, 64);
    if (lane < S_) c2_s[lane] = c2p;
  }
  __syncthreads();

  // ---- Phase A ----
  {
    const float sc = fminf(fmaxf(__expf(log_scales[n]), 0.1f), 2.0f);
    const float inv2 = 0.5f / (sc * sc);
    // uniform-scale fast path: x2 is a per-token constant in the softmax
    const bool uni =
        (__ballot(sc == __shfl(sc, 0, 64)) == 0xFFFFFFFFFFFFFFFFull);

    const float* xrow = x + ((size_t)b * T_ + tw + n) * D_ + (g << 3);
    f32x4 acc = {0.f, 0.f, 0.f, 0.f};
    float x2p = 0.f;

    if (uni) {
#pragma unroll
      for (int st = 0; st < 16; ++st) {
        float4 x0 = *(const float4*)(xrow + st * 32);
        float4 x1 = *(const float4*)(xrow + st * 32 + 4);
        acc = __builtin_amdgcn_mfma_f32_16x16x32_bf16(pack8(x0, x1),
                                                      cf_s[st][lane], acc,
                                                      0, 0, 0);
      }
    } else {
#pragma unroll
      for (int st = 0; st < 16; ++st) {
        float4 x0 = *(const float4*)(xrow + st * 32);
        float4 x1 = *(const float4*)(xrow + st * 32 + 4);
        x2p += dot4(x0, x0) + dot4(x1, x1);
        acc = __builtin_amdgcn_mfma_f32_16x16x32_bf16(pack8(x0, x1),
                                                      cf_s[st][lane], acc,
                                                      0, 0, 0);
      }
      x2p += __shfl_xor(x2p, 16, 64);
      x2p += __shfl_xor(x2p, 32, 64);  // x2 for token tw+n (all lanes)
    }

    const float c2 = c2_s[n];

    // logits: lane holds splat n, token rows (g*4+r)  [R5-verified layout]
    float lg[4];
#pragma unroll
    for (int r = 0; r < 4; ++r) {
      float t = 2.f * acc[r] - c2;
      if (!uni) t -= __shfl(x2p, (lane & 48) | ((g << 2) + r), 64);
      lg[r] = t * inv2;
    }

    // softmax across splats (16-lane groups), 4 tokens per lane (R5-verified)
    float mx[4] = {lg[0], lg[1], lg[2], lg[3]};
#pragma unroll
    for (int dlt = 1; dlt < 16; dlt <<= 1)
#pragma unroll
      for (int r = 0; r < 4; ++r) mx[r] = fmaxf(mx[r], __shfl_xor(mx[r], dlt, 64));
    float ev[4], sm[4];
#pragma unroll
    for (int r = 0; r < 4; ++r) { ev[r] = __expf(lg[r] - mx[r]); sm[r] = ev[r]; }
#pragma unroll
    for (int dlt = 1; dlt < 16; dlt <<= 1)
#pragma unroll
      for (int r = 0; r < 4; ++r) sm[r] += __shfl_xor(sm[r], dlt, 64);

    float* ar = attn + ((size_t)b * T_ + tw) * S_;
#pragma unroll
    for (int r = 0; r < 4; ++r) {
      float av = ev[r] / sm[r];
      int trow = (g << 2) + r;
      ar[trow * S_ + n] = av;
      a_s[(w << 4) + trow][n] = av;
    }
  }

  __syncthreads();

  // ---- Phase B (exact R0/R5, proven) ----
  {
    const int d = tid;  // owns cols d and d+256
    float2 acc[S_];
#pragma unroll
    for (int si = 0; si < S_; ++si) acc[si] = make_float2(0.f, 0.f);

    const float* xb = x + ((size_t)b * T_ + t0) * D_;

#pragma unroll 8
    for (int t = 0; t < CHUNK; ++t) {
      float xv0 = xb[(size_t)t * D_ + d];
      float xv1 = xb[(size_t)t * D_ + d + 256];
      const float4* ap = (const float4*)a_s[t];  // LDS broadcast
      float4 q0 = ap[0], q1 = ap[1], q2 = ap[2], q3 = ap[3];
      float av[S_] = {q0.x, q0.y, q0.z, q0.w, q1.x, q1.y, q1.z, q1.w,
                      q2.x, q2.y, q2.z, q2.w, q3.x, q3.y, q3.z, q3.w};
#pragma unroll
      for (int si = 0; si < S_; ++si) {
        acc[si].x += av[si] * xv0;
        acc[si].y += av[si] * xv1;
      }
    }

    float* tb = ts + (size_t)b * S_ * D_;
#pragma unroll
    for (int si = 0; si < S_; ++si) {
      atomicAdd(tb + si * D_ + d, acc[si].x);
      atomicAdd(tb + si * D_ + d + 256, acc[si].y);
    }
  }
}

// ---------------------------------------------------------------------------
// Kernel 2 (x2): out[r,e] = sum_k in[r,k] * W[e,k]   (r = 0..63 = b*S+s)
// Split-K=4 reduced in LDS (deterministic). 512 blocks x 256 threads.
// ---------------------------------------------------------------------------
__global__ __launch_bounds__(256) void proj_k(const float* __restrict__ in,
                                              const float* __restrict__ W,
                                              float* __restrict__ out) {
  __shared__ float red[4][64];
  const int r = blockIdx.x >> 3;
  const int eb = blockIdx.x & 7;
  const int el = threadIdx.x & 63;
  const int kc = threadIdx.x >> 6;
  const int e = (eb << 6) + el;

  const float4* w4 = (const float4*)(W + (size_t)e * D_ + kc * 128);
  const float4* i4 = (const float4*)(in + (size_t)r * D_ + kc * 128);
  float acc = 0.f;
#pragma unroll
  for (int k = 0; k < 32; ++k) acc += dot4(w4[k], i4[k]);

  red[kc][el] = acc;
  __syncthreads();
  if (kc == 0)
    out[(size_t)r * D_ + e] = red[0][el] + red[1][el] + red[2][el] + red[3][el];
}

// ---------------------------------------------------------------------------
// Kernel 3: out[b,t,e] = sum_s attn[b,t,s] * ss_o[b,s,e]
// EXACT R0 form (512 blocks, 64 tokens, float2 ssf): proven best inside the
// 177.5 total. (R2 float4 ssf: reg-step. R4 LDS+cap: worse. R6 K4_TOK=32:
// neutral.)
// ---------------------------------------------------------------------------
#define K4_TOK 64
__global__ __launch_bounds__(256) void out_k(const float* __restrict__ attn,
                                             const float* __restrict__ ss_o,
                                             float* __restrict__ out) {
  const int chunks = T_ / K4_TOK;  // 128
  const int b = blockIdx.x / chunks;
  const int t0 = (blockIdx.x % chunks) * K4_TOK;
  const int w = threadIdx.x >> 6;
  const int lane = threadIdx.x & 63;
  const int e0 = (w << 7) + (lane << 1);

  float2 ssf[S_];
  const float* sb = ss_o + (size_t)b * S_ * D_;
#pragma unroll
  for (int s = 0; s < S_; ++s) ssf[s] = *(const float2*)(sb + s * D_ + e0);

  const float4* ab = (const float4*)(attn + ((size_t)b * T_ + t0) * S_);
  float* ob = out + ((size_t)b * T_ + t0) * D_ + e0;

#pragma unroll 4
  for (int t = 0; t < K4_TOK; ++t) {
    float4 a0 = ab[t * 4 + 0], a1 = ab[t * 4 + 1];
    float4 a2 = ab[t * 4 + 2], a3 = ab[t * 4 + 3];
    float av[S_] = {a0.x, a0.y, a0.z, a0.w, a1.x, a1.y, a1.z, a1.w,
                    a2.x, a2.y, a2.z, a2.w, a3.x, a3.y, a3.z, a3.w};
    float2 acc = make_float2(0.f, 0.f);
#pragma unroll
    for (int s = 0; s < S_; ++s) {
      acc.x += av[s] * ssf[s].x;
      acc.y += av[s] * ssf[s].y;
    }
    *(float2*)(ob + (size_t)t * D_) = acc;
  }
}

// ---------------------------------------------------------------------------
extern "C" void kernel_launch(void* const* d_in, const int* in_sizes, int n_in,
                              void* d_out, int out_size, void* d_ws, size_t ws_size,
                              hipStream_t stream) {
  const float* x          = (const float*)d_in[0];  // [B,T,D]
  const float* centers    = (const float*)d_in[1];  // [S,D]
  const float* log_scales = (const float*)d_in[2];  // [S]
  const float* Wv         = (const float*)d_in[3];  // [D,D]
  const float* Wo         = (const float*)d_in[4];  // [D,D]
  float* out = (float*)d_out;                       // [B,T,D]

  // workspace layout (floats): attn | ts | tmp | ss_o
  float* attn = (float*)d_ws;                        // B*T*S   = 2 MB
  float* ts   = attn + (size_t)B_ * T_ * S_;         // B*S*D   = 128 KB
  float* tmp  = ts + (size_t)B_ * S_ * D_;           // B*S*D   = 128 KB
  float* ss_o = tmp + (size_t)B_ * S_ * D_;          // B*S*D   = 128 KB

  // zero only the atomic target (tiny, L2-resident fill)
  hipMemsetAsync(ts, 0, (size_t)B_ * S_ * D_ * sizeof(float), stream);

  attn_ts_k<<<B_ * (T_ / CHUNK), 256, 0, stream>>>(x, centers, log_scales, attn, ts);
  proj_k<<<512, 256, 0, stream>>>(ts, Wv, tmp);    // tmp = ts @ Wv^T
  proj_k<<<512, 256, 0, stream>>>(tmp, Wo, ss_o);  // ss_o = tmp @ Wo^T
  out_k<<<B_ * (T_ / K4_TOK), 256, 0, stream>>>(attn, ss_o, out);
}